// Round 7
// baseline (109.855 us; speedup 1.0000x reference)
//
#include <hip/hip_runtime.h>
#include <hip/hip_bf16.h>
#include <math.h>

typedef __attribute__((ext_vector_type(8))) short short8;
typedef __attribute__((ext_vector_type(4))) float f32x4;

constexpr int Hm = 512, Lm = 1024, Bm = 8;
constexpr int PAR = Hm * 64;
constexpr size_t PLANE = (size_t)Bm * Hm * Lm;   // 4194304 ushorts per plane

static __device__ __forceinline__ unsigned short f2bf(float f) {
    __hip_bfloat16 h = __float2bfloat16(f);
    return *reinterpret_cast<unsigned short*>(&h);
}
static __device__ __forceinline__ float bf2f(unsigned short u) {
    return __uint_as_float((unsigned)u << 16);
}
static __device__ __forceinline__ uint2 pack4(const unsigned short* x) {
    return make_uint2((unsigned)x[0] | ((unsigned)x[1] << 16),
                      (unsigned)x[2] | ((unsigned)x[3] << 16));
}

// par planes: 0 rr, 1 ri, 2 wr, 3 wi, 4 r64r, 5 r64i
__global__ void k0_params(const float* __restrict__ log_dt,
                          const float* __restrict__ log_A_real,
                          const float* __restrict__ A_imag,
                          const float* __restrict__ B_real,
                          const float* __restrict__ B_imag,
                          const float* __restrict__ C_real,
                          const float* __restrict__ C_imag,
                          float* __restrict__ par) {
    int idx = blockIdx.x * blockDim.x + threadIdx.x;
    if (idx >= PAR) return;
    int h = idx >> 6;
    double dt = exp((double)log_dt[h]);
    double Ar = -exp((double)log_A_real[idx]);
    double Ai = (double)A_imag[idx];
    double ar = Ar * dt, ai = Ai * dt;          // dtA
    double er = exp(ar);
    double rr = er * cos(ai), ri = er * sin(ai);        // r
    double nr = rr - 1.0, ni = ri;
    double den = Ar * Ar + Ai * Ai;
    double qr = (nr * Ar + ni * Ai) / den;
    double qi = (ni * Ar - nr * Ai) / den;
    double Br = (double)B_real[idx], Bi = (double)B_imag[idx];
    double bbr = qr * Br - qi * Bi, bbi = qr * Bi + qi * Br;
    double Cr = (double)C_real[idx], Ci = (double)C_imag[idx];
    double wr = Cr * bbr - Ci * bbi, wi = Cr * bbi + Ci * bbr;
    double e64 = exp(ar * 64.0);
    double p64 = ai * 64.0;
    par[0 * PAR + idx] = (float)rr;
    par[1 * PAR + idx] = (float)ri;
    par[2 * PAR + idx] = (float)wr;
    par[3 * PAR + idx] = (float)wi;
    par[4 * PAR + idx] = (float)(e64 * cos(p64));
    par[5 * PAR + idx] = (float)(e64 * sin(p64));
}

// conv_w f32 -> hi/lo bf16 planes
__global__ void k_cvt(const float* __restrict__ w,
                      unsigned short* __restrict__ oh,
                      unsigned short* __restrict__ ol) {
    int i = (blockIdx.x * 256 + threadIdx.x) * 4;
    float4 v = *(const float4*)&w[i];
    unsigned short h0 = f2bf(v.x), h1 = f2bf(v.y), h2 = f2bf(v.z), h3 = f2bf(v.w);
    unsigned short l0 = f2bf(v.x - bf2f(h0));
    unsigned short l1 = f2bf(v.y - bf2f(h1));
    unsigned short l2 = f2bf(v.z - bf2f(h2));
    unsigned short l3 = f2bf(v.w - bf2f(h3));
    *(uint2*)&oh[i] = make_uint2((unsigned)h0 | ((unsigned)h1 << 16),
                                 (unsigned)h2 | ((unsigned)h3 << 16));
    *(uint2*)&ol[i] = make_uint2((unsigned)l0 | ((unsigned)l1 << 16),
                                 (unsigned)l2 | ((unsigned)l3 << 16));
}

// Toeplitz block-conv via MFMA, G-array direct A-frag reads (no T build).
// One block per h, 4 waves. y_i(64x8) = sum_d T_d @ u_{i-d}; N=16 (2 i x 8 b).
// G[i] = K[i]  (so A[m][k'] = G[1023-64d-m+k'] = K[1023-lag] = Kf[lag]);
// zeros for i in [1024,1088). Stored as 8 shifted replicas
// GHs/GLs[s][e] = G[e+s] so every lane's b128 read is 16B-aligned.
// LDS (76032 B):
//   GHs [0, 17536)   8 x 1096 ushorts (hi)
//   GLs [17536, 35072)
//   uh  [35072, 55552)  [16 jc][2 ks][8 b][40] ushorts (hi)
//   ul  [55552, 76032)
//   phase0 scratch kl (per wave [32][67] f32) overlays uh/ul region
__global__ __launch_bounds__(256, 2) void k_tconv(const float* __restrict__ u,
                                                  const float* __restrict__ Dvec,
                                                  const float* __restrict__ par,
                                                  unsigned short* __restrict__ YbfH,
                                                  unsigned short* __restrict__ YbfL) {
    __shared__ __align__(16) char smem[76032];
    unsigned short* GHs = (unsigned short*)smem;
    unsigned short* GLs = (unsigned short*)(smem + 17536);
    unsigned short* uh  = (unsigned short*)(smem + 35072);
    unsigned short* ul  = (unsigned short*)(smem + 55552);

    const int tid = threadIdx.x, lane = tid & 63, wid = tid >> 6;
    const int h = blockIdx.x;
    const int fr = lane & 15, fq = lane >> 4;
    const short8 z8 = {};

    // zero-pad region i in [1024,1088) across all replicas
    if (tid < 64) {
        int i = 1024 + tid;
        #pragma unroll
        for (int s8 = 0; s8 < 8; ++s8) {
            GHs[s8 * 1096 + i - s8] = 0;
            GLs[s8 * 1096 + i - s8] = 0;
        }
    }

    // ---- phase 0: K[j] = Re(sum_n w_n r_n^j) -> hi/lo replicas (G[j]=K[j]) ----
    {
        float* kl = (float*)(smem + 35072) + wid * 2144;   // [32][67]
        const int pidx = h * 64 + lane;
        const float rrf = par[0 * PAR + pidx], rif = par[1 * PAR + pidx];
        float pr = par[2 * PAR + pidx], pi = par[3 * PAR + pidx];   // w
        float br = par[4 * PAR + pidx], bi = par[5 * PAR + pidx];   // r^64
        int cc = wid * 4;
        while (cc) {   // p = w * (r^64)^(4*wid)
            if (cc & 1) { float t_ = pr * br - pi * bi; pi = fmaf(pr, bi, pi * br); pr = t_; }
            float t2 = br * br - bi * bi; bi = 2.f * br * bi; br = t2;
            cc >>= 1;
        }
        for (int q = 0; q < 8; ++q) {
            #pragma unroll
            for (int j = 0; j < 32; ++j) {
                kl[j * 67 + lane] = pr;
                float t_ = pr * rrf - pi * rif; pi = fmaf(pr, rif, pi * rrf); pr = t_;
            }
            asm volatile("s_waitcnt lgkmcnt(0)" ::: "memory");
            const int jj = lane & 31, nh = (lane >> 5) * 32;
            float s0 = 0.f, s1 = 0.f;
            #pragma unroll
            for (int n = 0; n < 32; n += 4) {
                float2 a = *(const float2*)&kl[jj * 67 + nh + n];
                float2 b2 = *(const float2*)&kl[jj * 67 + nh + n + 2];
                s0 += a.x + a.y; s1 += b2.x + b2.y;
            }
            float s = s0 + s1;
            s += __shfl_xor(s, 32);
            if (lane < 32) {
                int jg = wid * 256 + q * 32 + lane;
                int i = jg;                       // G[i] = K[i]  (R6 bug: was 1023-jg)
                unsigned short hb = f2bf(s);
                unsigned short lb = f2bf(s - bf2f(hb));
                #pragma unroll
                for (int s8 = 0; s8 < 8; ++s8) {
                    int e = i - s8;
                    if (e >= 0) { GHs[s8 * 1096 + e] = hb; GLs[s8 * 1096 + e] = lb; }
                }
            }
            asm volatile("s_waitcnt lgkmcnt(0)" ::: "memory");
        }
    }
    __syncthreads();

    // ---- phase 1: stage u -> bf16 hi/lo B-operand layout ----
    {
        const int b = tid >> 5, l32 = tid & 31;
        const float* ub = u + ((size_t)(b * 512 + h)) * 1024;
        #pragma unroll
        for (int g = 0; g < 8; ++g) {
            int s = l32 * 4 + g * 128;
            float4 v = *(const float4*)&ub[s];
            unsigned short th[4], tl[4];
            th[0] = f2bf(v.x); tl[0] = f2bf(v.x - bf2f(th[0]));
            th[1] = f2bf(v.y); tl[1] = f2bf(v.y - bf2f(th[1]));
            th[2] = f2bf(v.z); tl[2] = f2bf(v.z - bf2f(th[2]));
            th[3] = f2bf(v.w); tl[3] = f2bf(v.w - bf2f(th[3]));
            int jc = s >> 6, ks = (s >> 5) & 1, k0 = s & 31;
            int off = ((jc * 2 + ks) * 8 + b) * 40 + k0;
            *(uint2*)&uh[off] = pack4(th);
            *(uint2*)&ul[off] = pack4(tl);
        }
    }
    __syncthreads();

    const float Dh = Dvec[h];
    f32x4 acc[2][4] = {};          // [pair][mf]
    const int i_lo2[2] = { wid, 7 - wid };
    const int i_hi2[2] = { wid + 8, 15 - wid };

    // per-lane replica + aligned base: i0 = 1023-64d-m+32ks+8fq, i0 mod 8 const
    const int sA = 7 - (fr & 7);
    const int base0 = 1023 - fr - sA;           // 1016 (fr<8) or 1008 (fr>=8)
    const unsigned short* gAh0 = GHs + sA * 1096 + base0 + fq * 8;
    const unsigned short* gAl0 = GLs + sA * 1096 + base0 + fq * 8;

    // register ring of A windows: W = 4d + mf - 2ks + 2, elem off = 32 - 16W
    short8 Fh[8], Fl[8];
#define LOADW(W) { Fh[(W) & 7] = *(const short8*)(gAh0 + (32 - 16 * (W))); \
                   Fl[(W) & 7] = *(const short8*)(gAl0 + (32 - 16 * (W))); }

    // ---- phase 2: d-loop (no barriers, no LDS writes) ----
    #pragma unroll
    for (int d = 0; d < 16; ++d) {
        if (d == 0) { LOADW(0); LOADW(1); LOADW(2); LOADW(3); LOADW(4); LOADW(5); }
        else { LOADW(4 * d + 2); LOADW(4 * d + 3); LOADW(4 * d + 4); LOADW(4 * d + 5); }
        #pragma unroll
        for (int p = 0; p < 2; ++p) {
            if (i_hi2[p] < d) continue;
            int jmine = ((fr >> 3) ? i_hi2[p] : i_lo2[p]) - d;
            bool vv = jmine >= 0;
            int ja = vv ? jmine : 0;
            #pragma unroll
            for (int ks = 0; ks < 2; ++ks) {
                int uoff = ((ja * 2 + ks) * 8 + (fr & 7)) * 40 + fq * 8;
                short8 bh = *(const short8*)&uh[uoff];
                short8 bl = *(const short8*)&ul[uoff];
                if (!vv) { bh = z8; bl = z8; }
                #pragma unroll
                for (int mf = 0; mf < 4; ++mf) {
                    const int sl = (4 * d + mf - 2 * ks + 2) & 7;
                    acc[p][mf] = __builtin_amdgcn_mfma_f32_16x16x32_bf16(Fh[sl], bh, acc[p][mf], 0, 0, 0);
                    acc[p][mf] = __builtin_amdgcn_mfma_f32_16x16x32_bf16(Fh[sl], bl, acc[p][mf], 0, 0, 0);
                    acc[p][mf] = __builtin_amdgcn_mfma_f32_16x16x32_bf16(Fl[sl], bh, acc[p][mf], 0, 0, 0);
                }
            }
        }
    }
#undef LOADW

    // ---- epilogue: y + D*u, gelu, hi/lo write ----
    #pragma unroll
    for (int p = 0; p < 2; ++p) {
        const int i_mine = (fr >> 3) ? i_hi2[p] : i_lo2[p];
        const int b = fr & 7;
        unsigned short* dsth = YbfH + ((size_t)(b * 512 + h)) * 1024 + i_mine * 64;
        unsigned short* dstl = YbfL + ((size_t)(b * 512 + h)) * 1024 + i_mine * 64;
        #pragma unroll
        for (int mf = 0; mf < 4; ++mf) {
            unsigned short oh[4], ol[4];
            #pragma unroll
            for (int j = 0; j < 4; ++j) {
                int tp = mf * 16 + fq * 4 + j;
                int uoff = ((i_mine * 2 + (tp >> 5)) * 8 + b) * 40 + (tp & 31);
                float uv = bf2f(uh[uoff]) + bf2f(ul[uoff]);
                float y = acc[p][mf][j] + Dh * uv;
                float g = 0.5f * y * (1.0f + erff(y * 0.70710678118654752f));
                oh[j] = f2bf(g);
                ol[j] = f2bf(g - bf2f(oh[j]));
            }
            int toff = mf * 16 + fq * 4;
            *(uint2*)&dsth[toff] = pack4(oh);
            *(uint2*)&dstl[toff] = pack4(ol);
        }
    }
}

// transpose [b][c][l] -> [b][l][c] per plane; blockIdx.z = plane*8 + b
__global__ __launch_bounds__(256) void k_tr(const unsigned short* __restrict__ Ybf,
                                            unsigned short* __restrict__ Ytb) {
    __shared__ unsigned short tl[64][72];
    const int t = threadIdx.x;
    const int zz = blockIdx.z;
    const int p = zz >> 3, b = zz & 7;
    const unsigned short* srcp = Ybf + (size_t)p * PLANE;
    unsigned short* dstp = Ytb + (size_t)p * PLANE;
    const int c0 = blockIdx.y * 64, l0 = blockIdx.x * 64;
    {
        const int c = t >> 2, lq = (t & 3) * 16;
        const unsigned short* src = srcp + ((size_t)(b * 512 + c0 + c)) * 1024 + l0 + lq;
        uint4 v0 = *(const uint4*)src;
        uint4 v1 = *(const uint4*)(src + 8);
        *(uint4*)&tl[c][lq] = v0;
        *(uint4*)&tl[c][lq + 8] = v1;
    }
    __syncthreads();
    {
        const int l = t >> 2, cq = (t & 3) * 16;
        unsigned int o[8];
        #pragma unroll
        for (int k = 0; k < 8; ++k)
            o[k] = (unsigned)tl[cq + 2 * k][l] | ((unsigned)tl[cq + 2 * k + 1][l] << 16);
        unsigned short* dst = dstp + ((size_t)(b * 1024 + l0 + l)) * 512 + c0 + cq;
        *(uint4*)dst = *(uint4*)&o[0];
        *(uint4*)(dst + 8) = *(uint4*)&o[4];
    }
}

// split-bf16 MFMA GEMM (hh, hl, lh) + bias/GLU/pool/dec epilogue
__global__ __launch_bounds__(256) void k2_gemm(const unsigned short* __restrict__ WbfH,
                                               const unsigned short* __restrict__ WbfL,
                                               const unsigned short* __restrict__ YtbH,
                                               const unsigned short* __restrict__ YtbL,
                                               const float* __restrict__ conv_b,
                                               const float* __restrict__ dec_w,
                                               float* __restrict__ partial) {
    __shared__ unsigned short WTh[128][40], WTl[128][40];
    __shared__ unsigned short YTh[128][40], YTl[128][40];
    __shared__ float red[4][64][20];
    const int tid = threadIdx.x, lane = tid & 63, wid = tid >> 6;
    const int b = blockIdx.z, oblk = blockIdx.y, lblk = blockIdx.x;
    const int o0 = oblk * 64, l0 = lblk * 128;
    const int fr = lane & 15, fq = lane >> 4;

    f32x4 acc[8][2] = {};

    const int srow = tid >> 1, skh = (tid & 1) * 16;
    const int grow = (srow < 64) ? (o0 + srow) : (512 + o0 + srow - 64);
    const size_t woff = (size_t)grow * 512 + skh;
    const size_t yoff = ((size_t)(b * 1024) + l0 + srow) * 512 + skh;

    for (int c0 = 0; c0 < 512; c0 += 32) {
        __syncthreads();
        uint4 wh0 = *(const uint4*)(WbfH + woff + c0);
        uint4 wh1 = *(const uint4*)(WbfH + woff + c0 + 8);
        uint4 wl0 = *(const uint4*)(WbfL + woff + c0);
        uint4 wl1 = *(const uint4*)(WbfL + woff + c0 + 8);
        uint4 yh0 = *(const uint4*)(YtbH + yoff + c0);
        uint4 yh1 = *(const uint4*)(YtbH + yoff + c0 + 8);
        uint4 yl0 = *(const uint4*)(YtbL + yoff + c0);
        uint4 yl1 = *(const uint4*)(YtbL + yoff + c0 + 8);
        *(uint4*)&WTh[srow][skh]     = wh0;
        *(uint4*)&WTh[srow][skh + 8] = wh1;
        *(uint4*)&WTl[srow][skh]     = wl0;
        *(uint4*)&WTl[srow][skh + 8] = wl1;
        *(uint4*)&YTh[srow][skh]     = yh0;
        *(uint4*)&YTh[srow][skh + 8] = yh1;
        *(uint4*)&YTl[srow][skh]     = yl0;
        *(uint4*)&YTl[srow][skh + 8] = yl1;
        __syncthreads();
        short8 b0h = *(const short8*)&YTh[wid * 32 + fr][fq * 8];
        short8 b1h = *(const short8*)&YTh[wid * 32 + 16 + fr][fq * 8];
        short8 b0l = *(const short8*)&YTl[wid * 32 + fr][fq * 8];
        short8 b1l = *(const short8*)&YTl[wid * 32 + 16 + fr][fq * 8];
        #pragma unroll
        for (int mf = 0; mf < 8; ++mf) {
            short8 ah = *(const short8*)&WTh[mf * 16 + fr][fq * 8];
            short8 al = *(const short8*)&WTl[mf * 16 + fr][fq * 8];
            acc[mf][0] = __builtin_amdgcn_mfma_f32_16x16x32_bf16(ah, b0h, acc[mf][0], 0, 0, 0);
            acc[mf][1] = __builtin_amdgcn_mfma_f32_16x16x32_bf16(ah, b1h, acc[mf][1], 0, 0, 0);
            acc[mf][0] = __builtin_amdgcn_mfma_f32_16x16x32_bf16(ah, b0l, acc[mf][0], 0, 0, 0);
            acc[mf][1] = __builtin_amdgcn_mfma_f32_16x16x32_bf16(ah, b1l, acc[mf][1], 0, 0, 0);
            acc[mf][0] = __builtin_amdgcn_mfma_f32_16x16x32_bf16(al, b0h, acc[mf][0], 0, 0, 0);
            acc[mf][1] = __builtin_amdgcn_mfma_f32_16x16x32_bf16(al, b1h, acc[mf][1], 0, 0, 0);
        }
    }

    #pragma unroll
    for (int mf = 0; mf < 4; ++mf)
        #pragma unroll
        for (int j = 0; j < 4; ++j) {
            int ol = mf * 16 + fq * 4 + j;
            float ba = conv_b[o0 + ol];
            float bb = conv_b[512 + o0 + ol];
            float s = 0.f;
            #pragma unroll
            for (int nf = 0; nf < 2; ++nf) {
                float za = acc[mf][nf][j] + ba;
                float zb = acc[mf + 4][nf][j] + bb;
                s += za / (1.f + expf(-zb));
            }
            red[wid][ol][fr] = s;
        }
    __syncthreads();
    if (tid < 64) {
        float s = 0.f;
        #pragma unroll
        for (int w = 0; w < 4; ++w) {
            float4 r0 = *(const float4*)&red[w][tid][0];
            float4 r1 = *(const float4*)&red[w][tid][4];
            float4 r2 = *(const float4*)&red[w][tid][8];
            float4 r3 = *(const float4*)&red[w][tid][12];
            s += (r0.x + r0.y + r0.z + r0.w) + (r1.x + r1.y + r1.z + r1.w)
               + (r2.x + r2.y + r2.z + r2.w) + (r3.x + r3.y + r3.z + r3.w);
        }
        float val = s * dec_w[o0 + tid] * (1.0f / 1024.0f);
        #pragma unroll
        for (int off = 32; off; off >>= 1) val += __shfl_xor(val, off);
        if (tid == 0) partial[((b * 8) + oblk) * 8 + lblk] = val;
    }
}

__global__ void k3_final(const float* __restrict__ partial,
                         const float* __restrict__ dec_b,
                         float* __restrict__ out) {
    int b = threadIdx.x;
    if (b < Bm) {
        float s = dec_b[0];
        for (int i = 0; i < 64; ++i) s += partial[b * 64 + i];
        out[b] = s;
    }
}

extern "C" void kernel_launch(void* const* d_in, const int* in_sizes, int n_in,
                              void* d_out, int out_size, void* d_ws, size_t ws_size,
                              hipStream_t stream) {
    const float* u          = (const float*)d_in[0];
    const float* log_dt     = (const float*)d_in[1];
    const float* log_A_real = (const float*)d_in[2];
    const float* A_imag     = (const float*)d_in[3];
    const float* B_real     = (const float*)d_in[4];
    const float* B_imag     = (const float*)d_in[5];
    const float* C_real     = (const float*)d_in[6];
    const float* C_imag     = (const float*)d_in[7];
    const float* Dvec       = (const float*)d_in[8];
    const float* conv_w     = (const float*)d_in[9];
    const float* conv_b     = (const float*)d_in[10];
    const float* dec_w      = (const float*)d_in[11];
    const float* dec_b      = (const float*)d_in[12];

    char* base = (char*)d_ws;
    float* par          = (float*)base;                                   // 768 KB
    unsigned short* Ybf = (unsigned short*)(base + 786432);               // 16 MB (hi|lo)
    unsigned short* Ytb = (unsigned short*)(base + 786432 + 16777216);    // 16 MB (hi|lo)
    unsigned short* Wh  = (unsigned short*)(base + 34340864);             // 1 MB
    unsigned short* Wl  = (unsigned short*)(base + 35389440);             // 1 MB
    float* partial      = (float*)(base + 36438016);                      // 2 KB
    float* out          = (float*)d_out;

    unsigned short* YbfH = Ybf;
    unsigned short* YbfL = Ybf + PLANE;
    unsigned short* YtbH = Ytb;
    unsigned short* YtbL = Ytb + PLANE;

    k0_params<<<128, 256, 0, stream>>>(log_dt, log_A_real, A_imag, B_real,
                                       B_imag, C_real, C_imag, par);
    k_cvt<<<512, 256, 0, stream>>>(conv_w, Wh, Wl);
    k_tconv<<<512, 256, 0, stream>>>(u, Dvec, par, YbfH, YbfL);
    k_tr<<<dim3(16, 8, 16), 256, 0, stream>>>(Ybf, Ytb);
    k2_gemm<<<dim3(8, 8, 8), 256, 0, stream>>>(Wh, Wl, YtbH, YtbL, conv_b, dec_w, partial);
    k3_final<<<1, 64, 0, stream>>>(partial, dec_b, out);
}

// Round 8
// 90.886 us; speedup vs baseline: 1.2087x; 1.2087x over previous
//
#include <hip/hip_runtime.h>
#include <hip/hip_bf16.h>
#include <math.h>

typedef __attribute__((ext_vector_type(8))) short short8;
typedef __attribute__((ext_vector_type(4))) float f32x4;
typedef __attribute__((ext_vector_type(4))) unsigned int uint4v;

constexpr int Hm = 512, Lm = 1024, Bm = 8;
constexpr int PAR = Hm * 64;
constexpr size_t PLANE = (size_t)Bm * Hm * Lm;   // 4194304 ushorts per plane

static __device__ __forceinline__ unsigned short f2bf(float f) {
    __hip_bfloat16 h = __float2bfloat16(f);
    return *reinterpret_cast<unsigned short*>(&h);
}
static __device__ __forceinline__ float bf2f(unsigned short u) {
    return __uint_as_float((unsigned)u << 16);
}
static __device__ __forceinline__ uint2 pack4(const unsigned short* x) {
    return make_uint2((unsigned)x[0] | ((unsigned)x[1] << 16),
                      (unsigned)x[2] | ((unsigned)x[3] << 16));
}

// par planes: 0 rr, 1 ri, 2 wr, 3 wi, 4 r64r, 5 r64i
__global__ void k0_params(const float* __restrict__ log_dt,
                          const float* __restrict__ log_A_real,
                          const float* __restrict__ A_imag,
                          const float* __restrict__ B_real,
                          const float* __restrict__ B_imag,
                          const float* __restrict__ C_real,
                          const float* __restrict__ C_imag,
                          float* __restrict__ par) {
    int idx = blockIdx.x * blockDim.x + threadIdx.x;
    if (idx >= PAR) return;
    int h = idx >> 6;
    double dt = exp((double)log_dt[h]);
    double Ar = -exp((double)log_A_real[idx]);
    double Ai = (double)A_imag[idx];
    double ar = Ar * dt, ai = Ai * dt;          // dtA
    double er = exp(ar);
    double rr = er * cos(ai), ri = er * sin(ai);        // r
    double nr = rr - 1.0, ni = ri;
    double den = Ar * Ar + Ai * Ai;
    double qr = (nr * Ar + ni * Ai) / den;
    double qi = (ni * Ar - nr * Ai) / den;
    double Br = (double)B_real[idx], Bi = (double)B_imag[idx];
    double bbr = qr * Br - qi * Bi, bbi = qr * Bi + qi * Br;
    double Cr = (double)C_real[idx], Ci = (double)C_imag[idx];
    double wr = Cr * bbr - Ci * bbi, wi = Cr * bbi + Ci * bbr;
    double e64 = exp(ar * 64.0);
    double p64 = ai * 64.0;
    par[0 * PAR + idx] = (float)rr;
    par[1 * PAR + idx] = (float)ri;
    par[2 * PAR + idx] = (float)wr;
    par[3 * PAR + idx] = (float)wi;
    par[4 * PAR + idx] = (float)(e64 * cos(p64));
    par[5 * PAR + idx] = (float)(e64 * sin(p64));
}

// conv_w f32 -> hi/lo bf16 planes
__global__ void k_cvt(const float* __restrict__ w,
                      unsigned short* __restrict__ oh,
                      unsigned short* __restrict__ ol) {
    int i = (blockIdx.x * 256 + threadIdx.x) * 4;
    float4 v = *(const float4*)&w[i];
    unsigned short h0 = f2bf(v.x), h1 = f2bf(v.y), h2 = f2bf(v.z), h3 = f2bf(v.w);
    unsigned short l0 = f2bf(v.x - bf2f(h0));
    unsigned short l1 = f2bf(v.y - bf2f(h1));
    unsigned short l2 = f2bf(v.z - bf2f(h2));
    unsigned short l3 = f2bf(v.w - bf2f(h3));
    *(uint2*)&oh[i] = make_uint2((unsigned)h0 | ((unsigned)h1 << 16),
                                 (unsigned)h2 | ((unsigned)h3 << 16));
    *(uint2*)&ol[i] = make_uint2((unsigned)l0 | ((unsigned)l1 << 16),
                                 (unsigned)l2 | ((unsigned)l3 << 16));
}

// Toeplitz block-conv via MFMA. Grid (h, parity): block handles output chunks
// i in {par, par+2, ..., par+14}; wave wid owns pair (2wid+par, 14-2wid+par).
// y_i(64x8) = sum_d T_d @ u_{i-d}; N=16 = (2 i via fr-groups) x 8 batches.
// G[idx] = K[idx] (A[t'][k] = G[1023-64d-16mf-fr+32ks+8fq+e]); zeros idx>1023.
// 2 shifted replicas (b32-aligned per-lane reads): GH2/GL2[s][e] = G[e+s],
// RLEN 1090 (bank-spread). u staged single-bf16 (hi only).
// LDS 29200 B: GH2 [0,4360) GL2 [4360,8720) uh [8720,29200)
//   phase0 scratch kl (per wave [16][66] f32 = 4224B) overlays uh.
__global__ __launch_bounds__(256, 4) void k_tconv(const float* __restrict__ u,
                                                  const float* __restrict__ Dvec,
                                                  const float* __restrict__ par,
                                                  unsigned short* __restrict__ YbfH,
                                                  unsigned short* __restrict__ YbfL) {
    __shared__ __align__(16) char smem[29200];
    unsigned short* GH2 = (unsigned short*)smem;            // 2 x 1090
    unsigned short* GL2 = (unsigned short*)(smem + 4360);   // 2 x 1090
    unsigned short* uh  = (unsigned short*)(smem + 8720);   // [16jc][2ks][8b][40]

    const int tid = threadIdx.x, lane = tid & 63, wid = tid >> 6;
    const int h = blockIdx.x >> 1;
    const int ipar = blockIdx.x & 1;
    const int fr = lane & 15, fq = lane >> 4;
    const short8 z8 = {};

    // zero-pad: rep0 e in [1024,1090), rep1 e in [1023,1090)
    if (tid < 67) {
        int e = 1023 + tid;
        GH2[1090 + e] = 0; GL2[1090 + e] = 0;
        if (tid >= 1) { GH2[e] = 0; GL2[e] = 0; }
    }

    // ---- phase 0: K[j] = Re(sum_n w_n r_n^j) -> hi/lo 2-replica G ----
    {
        float* kl = (float*)(smem + 8720) + wid * 1056;   // [16][66]
        const int pidx = h * 64 + lane;
        const float rrf = par[0 * PAR + pidx], rif = par[1 * PAR + pidx];
        float pr = par[2 * PAR + pidx], pi = par[3 * PAR + pidx];   // w
        float br = par[4 * PAR + pidx], bi = par[5 * PAR + pidx];   // r^64
        int cc = wid * 4;
        while (cc) {   // p = w * (r^64)^(4*wid)
            if (cc & 1) { float t_ = pr * br - pi * bi; pi = fmaf(pr, bi, pi * br); pr = t_; }
            float t2 = br * br - bi * bi; bi = 2.f * br * bi; br = t2;
            cc >>= 1;
        }
        const int jj = lane & 15, nq = lane >> 4;
        for (int q = 0; q < 16; ++q) {
            #pragma unroll
            for (int j = 0; j < 16; ++j) {
                kl[j * 66 + lane] = pr;
                float t_ = pr * rrf - pi * rif; pi = fmaf(pr, rif, pi * rrf); pr = t_;
            }
            asm volatile("s_waitcnt lgkmcnt(0)" ::: "memory");
            float s0 = 0.f, s1 = 0.f;
            #pragma unroll
            for (int n = 0; n < 16; n += 4) {
                float2 a = *(const float2*)&kl[jj * 66 + nq * 16 + n];
                float2 b2 = *(const float2*)&kl[jj * 66 + nq * 16 + n + 2];
                s0 += a.x + a.y; s1 += b2.x + b2.y;
            }
            float s = s0 + s1;
            s += __shfl_xor(s, 16);
            s += __shfl_xor(s, 32);
            if (lane < 16) {
                int jg = wid * 256 + q * 16 + jj;
                unsigned short hb = f2bf(s);
                unsigned short lb = f2bf(s - bf2f(hb));
                GH2[jg] = hb; GL2[jg] = lb;                         // rep0 e=jg
                if (jg >= 1) { GH2[1090 + jg - 1] = hb; GL2[1090 + jg - 1] = lb; }
            }
            asm volatile("s_waitcnt lgkmcnt(0)" ::: "memory");
        }
    }
    __syncthreads();

    // ---- phase 1: stage u -> bf16 (hi only) B-operand layout ----
    {
        const int b = tid >> 5, l32 = tid & 31;
        const float* ub = u + ((size_t)(b * 512 + h)) * 1024;
        #pragma unroll
        for (int g = 0; g < 8; ++g) {
            int s = l32 * 4 + g * 128;
            float4 v = *(const float4*)&ub[s];
            unsigned short t0 = f2bf(v.x), t1 = f2bf(v.y), t2 = f2bf(v.z), t3 = f2bf(v.w);
            int jc = s >> 6, ks = (s >> 5) & 1, k0 = s & 31;
            int off = ((jc * 2 + ks) * 8 + b) * 40 + k0;
            *(uint2*)&uh[off] = make_uint2((unsigned)t0 | ((unsigned)t1 << 16),
                                           (unsigned)t2 | ((unsigned)t3 << 16));
        }
    }
    __syncthreads();

    const float Dh = Dvec[h];
    const int i_lo = 2 * wid + ipar;
    const int i_hi = 14 - 2 * wid + ipar;
    f32x4 acc[4] = {};

    // per-lane replica + 4B-aligned base: G index = 1023-fr+8fq+32-16W+e
    const int sA = 1 - (fr & 1);
    const unsigned short* gAh0 = GH2 + sA * 1090 + (1023 - fr - sA) + fq * 8 + 32;
    const unsigned short* gAl0 = GL2 + sA * 1090 + (1023 - fr - sA) + fq * 8 + 32;

    short8 Fh[8], Fl[8];
#define LOADW(W) { \
    const unsigned int* ph_ = (const unsigned int*)(gAh0 - 16 * (W)); \
    const unsigned int* pl_ = (const unsigned int*)(gAl0 - 16 * (W)); \
    uint4v th_ = { ph_[0], ph_[1], ph_[2], ph_[3] }; \
    uint4v tl_ = { pl_[0], pl_[1], pl_[2], pl_[3] }; \
    Fh[(W) & 7] = __builtin_bit_cast(short8, th_); \
    Fl[(W) & 7] = __builtin_bit_cast(short8, tl_); }

    LOADW(0); LOADW(1); LOADW(2); LOADW(3); LOADW(4); LOADW(5);

    // ---- d-loop: fully unrolled, prefetch ring (W = 4d+mf-2ks+2) ----
    #pragma unroll
    for (int d = 0; d < 16; ++d) {
        if (d <= i_hi) {
            if (d < i_hi) { LOADW(4 * d + 6); LOADW(4 * d + 7); }
            {   // ks = 1 (W = 4d+mf)
                int jm = ((fr >> 3) ? i_hi : i_lo) - d;
                bool vv = jm >= 0;
                int ja = vv ? jm : 0;
                int uoff = ((ja * 2 + 1) * 8 + (fr & 7)) * 40 + fq * 8;
                short8 bh = *(const short8*)&uh[uoff];
                if (!vv) bh = z8;
                #pragma unroll
                for (int mf = 0; mf < 4; ++mf) {
                    const int sl = (4 * d + mf) & 7;
                    acc[mf] = __builtin_amdgcn_mfma_f32_16x16x32_bf16(Fh[sl], bh, acc[mf], 0, 0, 0);
                    acc[mf] = __builtin_amdgcn_mfma_f32_16x16x32_bf16(Fl[sl], bh, acc[mf], 0, 0, 0);
                }
            }
            if (d < i_hi) { LOADW(4 * d + 8); LOADW(4 * d + 9); }
            {   // ks = 0 (W = 4d+mf+2)
                int jm = ((fr >> 3) ? i_hi : i_lo) - d;
                bool vv = jm >= 0;
                int ja = vv ? jm : 0;
                int uoff = ((ja * 2 + 0) * 8 + (fr & 7)) * 40 + fq * 8;
                short8 bh = *(const short8*)&uh[uoff];
                if (!vv) bh = z8;
                #pragma unroll
                for (int mf = 0; mf < 4; ++mf) {
                    const int sl = (4 * d + mf + 2) & 7;
                    acc[mf] = __builtin_amdgcn_mfma_f32_16x16x32_bf16(Fh[sl], bh, acc[mf], 0, 0, 0);
                    acc[mf] = __builtin_amdgcn_mfma_f32_16x16x32_bf16(Fl[sl], bh, acc[mf], 0, 0, 0);
                }
            }
        }
    }
#undef LOADW

    // ---- epilogue: y + D*u, gelu, hi/lo write ----
    const int i_mine = (fr >> 3) ? i_hi : i_lo;
    const int bb = fr & 7;
    unsigned short* dsth = YbfH + ((size_t)(bb * 512 + h)) * 1024 + i_mine * 64;
    unsigned short* dstl = YbfL + ((size_t)(bb * 512 + h)) * 1024 + i_mine * 64;
    #pragma unroll
    for (int mf = 0; mf < 4; ++mf) {
        unsigned short oh[4], ol[4];
        #pragma unroll
        for (int j = 0; j < 4; ++j) {
            int tp = mf * 16 + fq * 4 + j;
            int uoff = ((i_mine * 2 + (tp >> 5)) * 8 + bb) * 40 + (tp & 31);
            float uv = bf2f(uh[uoff]);
            float y = acc[mf][j] + Dh * uv;
            float g = 0.5f * y * (1.0f + erff(y * 0.70710678118654752f));
            oh[j] = f2bf(g);
            ol[j] = f2bf(g - bf2f(oh[j]));
        }
        int toff = mf * 16 + fq * 4;
        *(uint2*)&dsth[toff] = pack4(oh);
        *(uint2*)&dstl[toff] = pack4(ol);
    }
}

// transpose [b][c][l] -> [b][l][c] per plane; blockIdx.z = plane*8 + b
__global__ __launch_bounds__(256) void k_tr(const unsigned short* __restrict__ Ybf,
                                            unsigned short* __restrict__ Ytb) {
    __shared__ unsigned short tl[64][72];
    const int t = threadIdx.x;
    const int zz = blockIdx.z;
    const int p = zz >> 3, b = zz & 7;
    const unsigned short* srcp = Ybf + (size_t)p * PLANE;
    unsigned short* dstp = Ytb + (size_t)p * PLANE;
    const int c0 = blockIdx.y * 64, l0 = blockIdx.x * 64;
    {
        const int c = t >> 2, lq = (t & 3) * 16;
        const unsigned short* src = srcp + ((size_t)(b * 512 + c0 + c)) * 1024 + l0 + lq;
        uint4 v0 = *(const uint4*)src;
        uint4 v1 = *(const uint4*)(src + 8);
        *(uint4*)&tl[c][lq] = v0;
        *(uint4*)&tl[c][lq + 8] = v1;
    }
    __syncthreads();
    {
        const int l = t >> 2, cq = (t & 3) * 16;
        unsigned int o[8];
        #pragma unroll
        for (int k = 0; k < 8; ++k)
            o[k] = (unsigned)tl[cq + 2 * k][l] | ((unsigned)tl[cq + 2 * k + 1][l] << 16);
        unsigned short* dst = dstp + ((size_t)(b * 1024 + l0 + l)) * 512 + c0 + cq;
        *(uint4*)dst = *(uint4*)&o[0];
        *(uint4*)(dst + 8) = *(uint4*)&o[4];
    }
}

// split-bf16 MFMA GEMM (hh, hl, lh) + bias/GLU/pool/dec epilogue
__global__ __launch_bounds__(256) void k2_gemm(const unsigned short* __restrict__ WbfH,
                                               const unsigned short* __restrict__ WbfL,
                                               const unsigned short* __restrict__ YtbH,
                                               const unsigned short* __restrict__ YtbL,
                                               const float* __restrict__ conv_b,
                                               const float* __restrict__ dec_w,
                                               float* __restrict__ partial) {
    __shared__ unsigned short WTh[128][40], WTl[128][40];
    __shared__ unsigned short YTh[128][40], YTl[128][40];
    __shared__ float red[4][64][20];
    const int tid = threadIdx.x, lane = tid & 63, wid = tid >> 6;
    const int b = blockIdx.z, oblk = blockIdx.y, lblk = blockIdx.x;
    const int o0 = oblk * 64, l0 = lblk * 128;
    const int fr = lane & 15, fq = lane >> 4;

    f32x4 acc[8][2] = {};

    const int srow = tid >> 1, skh = (tid & 1) * 16;
    const int grow = (srow < 64) ? (o0 + srow) : (512 + o0 + srow - 64);
    const size_t woff = (size_t)grow * 512 + skh;
    const size_t yoff = ((size_t)(b * 1024) + l0 + srow) * 512 + skh;

    for (int c0 = 0; c0 < 512; c0 += 32) {
        __syncthreads();
        uint4 wh0 = *(const uint4*)(WbfH + woff + c0);
        uint4 wh1 = *(const uint4*)(WbfH + woff + c0 + 8);
        uint4 wl0 = *(const uint4*)(WbfL + woff + c0);
        uint4 wl1 = *(const uint4*)(WbfL + woff + c0 + 8);
        uint4 yh0 = *(const uint4*)(YtbH + yoff + c0);
        uint4 yh1 = *(const uint4*)(YtbH + yoff + c0 + 8);
        uint4 yl0 = *(const uint4*)(YtbL + yoff + c0);
        uint4 yl1 = *(const uint4*)(YtbL + yoff + c0 + 8);
        *(uint4*)&WTh[srow][skh]     = wh0;
        *(uint4*)&WTh[srow][skh + 8] = wh1;
        *(uint4*)&WTl[srow][skh]     = wl0;
        *(uint4*)&WTl[srow][skh + 8] = wl1;
        *(uint4*)&YTh[srow][skh]     = yh0;
        *(uint4*)&YTh[srow][skh + 8] = yh1;
        *(uint4*)&YTl[srow][skh]     = yl0;
        *(uint4*)&YTl[srow][skh + 8] = yl1;
        __syncthreads();
        short8 b0h = *(const short8*)&YTh[wid * 32 + fr][fq * 8];
        short8 b1h = *(const short8*)&YTh[wid * 32 + 16 + fr][fq * 8];
        short8 b0l = *(const short8*)&YTl[wid * 32 + fr][fq * 8];
        short8 b1l = *(const short8*)&YTl[wid * 32 + 16 + fr][fq * 8];
        #pragma unroll
        for (int mf = 0; mf < 8; ++mf) {
            short8 ah = *(const short8*)&WTh[mf * 16 + fr][fq * 8];
            short8 al = *(const short8*)&WTl[mf * 16 + fr][fq * 8];
            acc[mf][0] = __builtin_amdgcn_mfma_f32_16x16x32_bf16(ah, b0h, acc[mf][0], 0, 0, 0);
            acc[mf][1] = __builtin_amdgcn_mfma_f32_16x16x32_bf16(ah, b1h, acc[mf][1], 0, 0, 0);
            acc[mf][0] = __builtin_amdgcn_mfma_f32_16x16x32_bf16(ah, b0l, acc[mf][0], 0, 0, 0);
            acc[mf][1] = __builtin_amdgcn_mfma_f32_16x16x32_bf16(ah, b1l, acc[mf][1], 0, 0, 0);
            acc[mf][0] = __builtin_amdgcn_mfma_f32_16x16x32_bf16(al, b0h, acc[mf][0], 0, 0, 0);
            acc[mf][1] = __builtin_amdgcn_mfma_f32_16x16x32_bf16(al, b1h, acc[mf][1], 0, 0, 0);
        }
    }

    #pragma unroll
    for (int mf = 0; mf < 4; ++mf)
        #pragma unroll
        for (int j = 0; j < 4; ++j) {
            int ol = mf * 16 + fq * 4 + j;
            float ba = conv_b[o0 + ol];
            float bb = conv_b[512 + o0 + ol];
            float s = 0.f;
            #pragma unroll
            for (int nf = 0; nf < 2; ++nf) {
                float za = acc[mf][nf][j] + ba;
                float zb = acc[mf + 4][nf][j] + bb;
                s += za / (1.f + expf(-zb));
            }
            red[wid][ol][fr] = s;
        }
    __syncthreads();
    if (tid < 64) {
        float s = 0.f;
        #pragma unroll
        for (int w = 0; w < 4; ++w) {
            float4 r0 = *(const float4*)&red[w][tid][0];
            float4 r1 = *(const float4*)&red[w][tid][4];
            float4 r2 = *(const float4*)&red[w][tid][8];
            float4 r3 = *(const float4*)&red[w][tid][12];
            s += (r0.x + r0.y + r0.z + r0.w) + (r1.x + r1.y + r1.z + r1.w)
               + (r2.x + r2.y + r2.z + r2.w) + (r3.x + r3.y + r3.z + r3.w);
        }
        float val = s * dec_w[o0 + tid] * (1.0f / 1024.0f);
        #pragma unroll
        for (int off = 32; off; off >>= 1) val += __shfl_xor(val, off);
        if (tid == 0) partial[((b * 8) + oblk) * 8 + lblk] = val;
    }
}

__global__ void k3_final(const float* __restrict__ partial,
                         const float* __restrict__ dec_b,
                         float* __restrict__ out) {
    int b = threadIdx.x;
    if (b < Bm) {
        float s = dec_b[0];
        for (int i = 0; i < 64; ++i) s += partial[b * 64 + i];
        out[b] = s;
    }
}

extern "C" void kernel_launch(void* const* d_in, const int* in_sizes, int n_in,
                              void* d_out, int out_size, void* d_ws, size_t ws_size,
                              hipStream_t stream) {
    const float* u          = (const float*)d_in[0];
    const float* log_dt     = (const float*)d_in[1];
    const float* log_A_real = (const float*)d_in[2];
    const float* A_imag     = (const float*)d_in[3];
    const float* B_real     = (const float*)d_in[4];
    const float* B_imag     = (const float*)d_in[5];
    const float* C_real     = (const float*)d_in[6];
    const float* C_imag     = (const float*)d_in[7];
    const float* Dvec       = (const float*)d_in[8];
    const float* conv_w     = (const float*)d_in[9];
    const float* conv_b     = (const float*)d_in[10];
    const float* dec_w      = (const float*)d_in[11];
    const float* dec_b      = (const float*)d_in[12];

    char* base = (char*)d_ws;
    float* par          = (float*)base;                                   // 768 KB
    unsigned short* Ybf = (unsigned short*)(base + 786432);               // 16 MB (hi|lo)
    unsigned short* Ytb = (unsigned short*)(base + 786432 + 16777216);    // 16 MB (hi|lo)
    unsigned short* Wh  = (unsigned short*)(base + 34340864);             // 1 MB
    unsigned short* Wl  = (unsigned short*)(base + 35389440);             // 1 MB
    float* partial      = (float*)(base + 36438016);                      // 2 KB
    float* out          = (float*)d_out;

    unsigned short* YbfH = Ybf;
    unsigned short* YbfL = Ybf + PLANE;
    unsigned short* YtbH = Ytb;
    unsigned short* YtbL = Ytb + PLANE;

    k0_params<<<128, 256, 0, stream>>>(log_dt, log_A_real, A_imag, B_real,
                                       B_imag, C_real, C_imag, par);
    k_cvt<<<512, 256, 0, stream>>>(conv_w, Wh, Wl);
    k_tconv<<<1024, 256, 0, stream>>>(u, Dvec, par, YbfH, YbfL);
    k_tr<<<dim3(16, 8, 16), 256, 0, stream>>>(Ybf, Ytb);
    k2_gemm<<<dim3(8, 8, 8), 256, 0, stream>>>(Wh, Wl, YtbH, YtbL, conv_b, dec_w, partial);
    k3_final<<<1, 64, 0, stream>>>(partial, dec_b, out);
}